// Round 4
// baseline (97.831 us; speedup 1.0000x reference)
//
#include <hip/hip_runtime.h>
#include <hip/hip_bf16.h>

// Problem constants
#define Bn 32
#define Nn 2048
#define Mn 12
#define FIN 64
#define FOUT 25
#define HPAD 28            // padded h row (floats) for float4 alignment
#define EPSBN 1e-5f

#define K1_BLOCKS 1056     // 32 b * 3 groups * 11 chunks(64 atoms)
#define NPART (K1_BLOCKS * 4)   // BN partial rows (4 x 16-lane groups of wave 0)
#define K3_BLOCKS 1024     // 32 chunks(64 atoms) * 32 b
#define NROWS 65536        // B*N

// ---------------------------------------------------------------------------
// K1: grouped linear + relu -> h[B][N][HPAD]; BN partials.
// 4-way K-split BY WAVE: block = 256 thr = 4 waves over the SAME 64 atoms;
// wave q owns input features [16q, 16q+16). q = tid>>6 is wave-uniform and g
// is block-uniform, so every weight index is (uniform base) x (compile-time
// offset) -> s_load weights, VALU is pure v_fmac. Waves 1-3 dump partial acc
// to LDS; wave 0 combines, applies bias+relu, stores h, and emits BN
// partials via in-register butterflies (no extra barriers).
// ---------------------------------------------------------------------------
__global__ __launch_bounds__(256) void k1_typelinear(
    const float* __restrict__ atom,      // [B][N][FIN]
    const float* __restrict__ type_w,    // [3][FIN][FOUT]
    const float* __restrict__ type_b,    // [3][FOUT]
    float* __restrict__ h,               // [B][N][HPAD]
    float* __restrict__ psum,            // [FOUT][NPART]
    float* __restrict__ psq)             // [FOUT][NPART]
{
    const int blk = blockIdx.x;
    const int b = blk / 33;
    const int rem = blk % 33;
    const int g = rem / 11;
    const int chunk = rem % 11;
    const int starts[4] = {0, 683, 1366, 2048};
    const int s0 = starts[g];
    const int e0 = starts[g + 1];
    const int tid = threadIdx.x;
    const int a = tid & 63;              // atom within chunk
    const int q = tid >> 6;              // feature quarter (wave-uniform)
    const int n = s0 + chunk * 64 + a;
    const bool act = (n < e0);

    float acc[FOUT];
    #pragma unroll
    for (int o = 0; o < FOUT; ++o) acc[o] = 0.0f;

    if (act) {
        // 16 input features for this quarter: 4 x float4
        float av[16];
        const float4* ap = reinterpret_cast<const float4*>(
            atom + ((size_t)b * Nn + n) * FIN + q * 16);
        #pragma unroll
        for (int i = 0; i < 4; ++i) {
            float4 v = ap[i];
            av[4 * i + 0] = v.x; av[4 * i + 1] = v.y;
            av[4 * i + 2] = v.z; av[4 * i + 3] = v.w;
        }
        const float* wg = type_w + (size_t)g * (FIN * FOUT) + q * 16 * FOUT;
        #pragma unroll
        for (int f = 0; f < 16; ++f) {
            const float x = av[f];
            #pragma unroll
            for (int o = 0; o < FOUT; ++o)
                acc[o] = fmaf(x, wg[f * FOUT + o], acc[o]);  // s_load weights
        }
    }

    __shared__ float sm[3][64][26];      // stride 26: 2-way conflict (free)
    if (q > 0) {
        #pragma unroll
        for (int o = 0; o < FOUT; ++o) sm[q - 1][a][o] = acc[o];
    }
    __syncthreads();
    if (q != 0) return;

    // wave 0: combine quarters, bias+relu, store h
    #pragma unroll
    for (int o = 0; o < FOUT; ++o)
        acc[o] += (sm[0][a][o] + sm[1][a][o]) + sm[2][a][o];

    if (act) {
        const float* bg = type_b + (size_t)g * FOUT;
        #pragma unroll
        for (int o = 0; o < FOUT; ++o)
            acc[o] = fmaxf(acc[o] + bg[o], 0.0f);
        float* hp = h + ((size_t)b * Nn + n) * HPAD;
        float4* hp4 = reinterpret_cast<float4*>(hp);
        #pragma unroll
        for (int i = 0; i < 6; ++i) {
            float4 v;
            v.x = acc[4 * i + 0]; v.y = acc[4 * i + 1];
            v.z = acc[4 * i + 2]; v.w = acc[4 * i + 3];
            hp4[i] = v;
        }
        hp[24] = acc[24];
    } else {
        #pragma unroll
        for (int o = 0; o < FOUT; ++o) acc[o] = 0.0f;
    }

    // BN partials: butterfly {1,2,4,8} -> per-16-lane-group sums
    float bs[FOUT], bq[FOUT];
    #pragma unroll
    for (int o = 0; o < FOUT; ++o) {
        float s = acc[o];
        float qq = acc[o] * acc[o];
        s += __shfl_xor(s, 1, 64);  qq += __shfl_xor(qq, 1, 64);
        s += __shfl_xor(s, 2, 64);  qq += __shfl_xor(qq, 2, 64);
        s += __shfl_xor(s, 4, 64);  qq += __shfl_xor(qq, 4, 64);
        s += __shfl_xor(s, 8, 64);  qq += __shfl_xor(qq, 8, 64);
        bs[o] = s; bq[o] = qq;
    }
    const int row = blk * 4 + (a >> 4);
    if ((a & 15) == 0) {
        #pragma unroll
        for (int o = 0; o < FOUT; ++o) {
            psum[(size_t)o * NPART + row] = bs[o];
            psq [(size_t)o * NPART + row] = bq[o];
        }
    }
}

// ---------------------------------------------------------------------------
// K2: reduce partials -> per-channel affine A, C.
// 25 blocks (one channel each) x 64 threads; coalesced float4 streams.
// ---------------------------------------------------------------------------
__global__ void k2_bnstats(
    const float* __restrict__ psum,      // [FOUT][NPART]
    const float* __restrict__ psq,       // [FOUT][NPART]
    const float* __restrict__ gamma,
    const float* __restrict__ beta,
    float* __restrict__ AC)              // [50]: A[0..24], C[25..49]
{
    const int c = blockIdx.x;            // channel 0..24
    const int lane = threadIdx.x;        // 64
    const float4* ps4 = reinterpret_cast<const float4*>(psum + (size_t)c * NPART);
    const float4* pq4 = reinterpret_cast<const float4*>(psq  + (size_t)c * NPART);
    float s1 = 0.0f, s2 = 0.0f;
    for (int i = lane; i < NPART / 4; i += 64) {
        float4 v = ps4[i]; s1 += (v.x + v.y) + (v.z + v.w);
        float4 q = pq4[i]; s2 += (q.x + q.y) + (q.z + q.w);
    }
    #pragma unroll
    for (int m = 1; m < 64; m <<= 1) {
        s1 += __shfl_xor(s1, m, 64);
        s2 += __shfl_xor(s2, m, 64);
    }
    if (lane == 0) {
        const float inv_cnt = 1.0f / (float)NROWS;
        const float mean = s1 * inv_cnt;
        const float var = s2 * inv_cnt - mean * mean;
        const float a = gamma[c] * rsqrtf(var + EPSBN);
        AC[c] = a;
        AC[FOUT + c] = beta[c] - mean * a;
    }
}

// ---------------------------------------------------------------------------
// K3: gather + BN-on-the-fly + conv linear + relu + out_w dot.
// 4 threads per atom (3 neighbors each) for the GATHER; after the width-4
// msg reduce, all 4 lanes run the full conv REDUNDANTLY with a uniform
// o-loop -> conv_w/conv_b/out_w are s_loads (no per-lane vector loads).
// The x4 double count is folded into k4's scale.
// XCD locality: b = blk & 31 -> blk%8 == b%8, one XCD per batch slab.
// ---------------------------------------------------------------------------
__global__ __launch_bounds__(256) void k3_conv(
    const float* __restrict__ h,         // [B][N][HPAD]
    const float* __restrict__ bond,      // [B][N][M]
    const int*   __restrict__ adj,       // [B][N][M]
    const float* __restrict__ AC,        // [50]
    const float* __restrict__ conv_w,    // [FOUT][FOUT]
    const float* __restrict__ conv_b,    // [FOUT]
    const float* __restrict__ out_w,     // [FOUT][1]
    float* __restrict__ pe)              // [K3_BLOCKS] block partials
{
    const int blk = blockIdx.x;
    const int b = blk & 31;
    const int chunk = blk >> 5;
    const int tid = threadIdx.x;
    const int a = tid >> 2;              // atom within chunk (0..63)
    const int mg = tid & 3;              // neighbor group (3 each)
    const int n = chunk * 64 + a;
    const size_t row = (size_t)b * Nn + n;

    const float* bp = bond + row * Mn + mg * 3;
    const int*   ajp = adj + row * Mn + mg * 3;
    const float w0 = bp[0], w1 = bp[1], w2 = bp[2];
    const int a0 = ajp[0], a1 = ajp[1], a2 = ajp[2];
    float bsum = w0 + w1 + w2;

    const float* hb = h + (size_t)b * Nn * HPAD;
    const float4* p0 = reinterpret_cast<const float4*>(hb + (size_t)a0 * HPAD);
    const float4* p1 = reinterpret_cast<const float4*>(hb + (size_t)a1 * HPAD);
    const float4* p2 = reinterpret_cast<const float4*>(hb + (size_t)a2 * HPAD);

    // issue all 21 gather loads up front (max MLP), then FMA
    float4 q0[7], q1[7], q2[7];
    #pragma unroll
    for (int i = 0; i < 7; ++i) q0[i] = p0[i];
    #pragma unroll
    for (int i = 0; i < 7; ++i) q1[i] = p1[i];
    #pragma unroll
    for (int i = 0; i < 7; ++i) q2[i] = p2[i];

    float msg[FOUT];
    #pragma unroll
    for (int i = 0; i < 6; ++i) {
        msg[4*i+0] = fmaf(w2, q2[i].x, fmaf(w1, q1[i].x, w0 * q0[i].x));
        msg[4*i+1] = fmaf(w2, q2[i].y, fmaf(w1, q1[i].y, w0 * q0[i].y));
        msg[4*i+2] = fmaf(w2, q2[i].z, fmaf(w1, q1[i].z, w0 * q0[i].z));
        msg[4*i+3] = fmaf(w2, q2[i].w, fmaf(w1, q1[i].w, w0 * q0[i].w));
    }
    msg[24] = fmaf(w2, q2[6].x, fmaf(w1, q1[6].x, w0 * q0[6].x));

    // reduce the 4 lanes of this atom (width-4 butterfly)
    #pragma unroll
    for (int f = 0; f < FOUT; ++f) {
        msg[f] += __shfl_xor(msg[f], 1, 64);
        msg[f] += __shfl_xor(msg[f], 2, 64);
    }
    bsum += __shfl_xor(bsum, 1, 64);
    bsum += __shfl_xor(bsum, 2, 64);

    // BN affine on the fly
    float msgn[FOUT];
    #pragma unroll
    for (int f = 0; f < FOUT; ++f)
        msgn[f] = AC[f] * msg[f] + AC[FOUT + f] * bsum;

    // full conv, uniform o-loop (redundant x4 across mg lanes; s_load weights)
    float v = 0.0f;
    #pragma unroll
    for (int o = 0; o < FOUT; ++o) {
        float t = conv_b[o];
        #pragma unroll
        for (int f = 0; f < FOUT; ++f)
            t = fmaf(msgn[f], conv_w[f * FOUT + o], t);
        v += fmaxf(t, 0.0f) * out_w[o];
    }

    // wave butterfly (16 atoms x 4 identical copies), then 4-wave LDS
    #pragma unroll
    for (int m = 1; m < 64; m <<= 1)
        v += __shfl_xor(v, m, 64);
    __shared__ float wsum[4];
    const int wid = tid >> 6;
    if ((tid & 63) == 0) wsum[wid] = v;
    __syncthreads();
    if (tid == 0)
        pe[blk] = wsum[0] + wsum[1] + wsum[2] + wsum[3];
}

// ---------------------------------------------------------------------------
// K4: final per-batch reduce + relu.  1 block, 32 threads.
// Scale 1/(4*Nn): each atom's conv value was summed 4x (redundant lanes).
// ---------------------------------------------------------------------------
__global__ void k4_final(
    const float* __restrict__ pe,        // [K3_BLOCKS], blk = chunk*32 + b
    const float* __restrict__ out_b,
    float* __restrict__ out)             // [B]
{
    const int b = threadIdx.x;
    if (b >= Bn) return;
    float s = 0.0f;
    #pragma unroll
    for (int c = 0; c < 32; ++c) s += pe[c * 32 + b];
    const float e = s * (1.0f / (4.0f * (float)Nn)) + out_b[0];
    out[b] = fmaxf(e, 0.0f);
}

// ---------------------------------------------------------------------------
extern "C" void kernel_launch(void* const* d_in, const int* in_sizes, int n_in,
                              void* d_out, int out_size, void* d_ws, size_t ws_size,
                              hipStream_t stream)
{
    const float* atom   = (const float*)d_in[0];
    const float* bond   = (const float*)d_in[1];
    const int*   adjm   = (const int*)  d_in[2];
    const float* type_w = (const float*)d_in[3];
    const float* type_b = (const float*)d_in[4];
    const float* gamma  = (const float*)d_in[5];
    const float* beta   = (const float*)d_in[6];
    const float* conv_w = (const float*)d_in[7];
    const float* conv_b = (const float*)d_in[8];
    const float* out_w  = (const float*)d_in[9];
    const float* out_b  = (const float*)d_in[10];
    float* out = (float*)d_out;

    float* ws = (float*)d_ws;
    float* h    = ws;                             // B*N*HPAD = 1,835,008
    float* psum = h + (size_t)Bn * Nn * HPAD;     // FOUT*NPART = 105,600
    float* psq  = psum + (size_t)FOUT * NPART;    // 105,600
    float* AC   = psq + (size_t)FOUT * NPART;     // 50 (pad 64)
    float* pe   = AC + 64;                        // 1024

    k1_typelinear<<<K1_BLOCKS, 256, 0, stream>>>(atom, type_w, type_b, h, psum, psq);
    k2_bnstats<<<FOUT, 64, 0, stream>>>(psum, psq, gamma, beta, AC);
    k3_conv<<<K3_BLOCKS, 256, 0, stream>>>(h, bond, adjm, AC, conv_w, conv_b, out_w, pe);
    k4_final<<<1, 32, 0, stream>>>(pe, out_b, out);
}

// Round 5
// 57.676 us; speedup vs baseline: 1.6962x; 1.6962x over previous
//
#include <hip/hip_runtime.h>
#include <hip/hip_bf16.h>

// Problem constants
#define Bn 32
#define Nn 2048
#define Mn 12
#define FIN 64
#define FOUT 25
#define HPAD 28            // padded h row (floats) for float4 alignment
#define EPSBN 1e-5f

#define K1_BLOCKS 1056     // 32 b * 3 groups * 11 chunks(64 atoms)
#define NPART (K1_BLOCKS * 4)   // BN partial rows (4 x 16-lane groups of wave 0)
#define K3_BLOCKS 1024     // 32 chunks(64 atoms) * 32 b
#define NROWS 65536        // B*N

// ---------------------------------------------------------------------------
// K1: grouped linear + relu -> h[B][N][HPAD]; BN partials.
// 4-way K-split BY WAVE: block = 256 thr = 4 waves over the SAME 64 atoms;
// wave q owns input features [16q, 16q+16). q = tid>>6 is wave-uniform and g
// is block-uniform, so every weight index is (uniform base) x (compile-time
// offset) -> s_load weights, VALU is pure v_fmac. Waves 1-3 dump partial acc
// to LDS; wave 0 combines, applies bias+relu, stores h, and emits BN
// partials via in-register butterflies.
// ---------------------------------------------------------------------------
__global__ __launch_bounds__(256) void k1_typelinear(
    const float* __restrict__ atom,      // [B][N][FIN]
    const float* __restrict__ type_w,    // [3][FIN][FOUT]
    const float* __restrict__ type_b,    // [3][FOUT]
    float* __restrict__ h,               // [B][N][HPAD]
    float* __restrict__ psum,            // [FOUT][NPART]
    float* __restrict__ psq)             // [FOUT][NPART]
{
    const int blk = blockIdx.x;
    const int b = blk / 33;
    const int rem = blk % 33;
    const int g = rem / 11;
    const int chunk = rem % 11;
    const int starts[4] = {0, 683, 1366, 2048};
    const int s0 = starts[g];
    const int e0 = starts[g + 1];
    const int tid = threadIdx.x;
    const int a = tid & 63;              // atom within chunk
    const int q = tid >> 6;              // feature quarter (wave-uniform)
    const int n = s0 + chunk * 64 + a;
    const bool act = (n < e0);

    float acc[FOUT];
    #pragma unroll
    for (int o = 0; o < FOUT; ++o) acc[o] = 0.0f;

    if (act) {
        // 16 input features for this quarter: 4 x float4
        float av[16];
        const float4* ap = reinterpret_cast<const float4*>(
            atom + ((size_t)b * Nn + n) * FIN + q * 16);
        #pragma unroll
        for (int i = 0; i < 4; ++i) {
            float4 v = ap[i];
            av[4 * i + 0] = v.x; av[4 * i + 1] = v.y;
            av[4 * i + 2] = v.z; av[4 * i + 3] = v.w;
        }
        const float* wg = type_w + (size_t)g * (FIN * FOUT) + q * 16 * FOUT;
        #pragma unroll
        for (int f = 0; f < 16; ++f) {
            const float x = av[f];
            #pragma unroll
            for (int o = 0; o < FOUT; ++o)
                acc[o] = fmaf(x, wg[f * FOUT + o], acc[o]);  // s_load weights
        }
    }

    __shared__ float sm[3][64][26];      // stride 26: 2-way conflict (free)
    if (q > 0) {
        #pragma unroll
        for (int o = 0; o < FOUT; ++o) sm[q - 1][a][o] = acc[o];
    }
    __syncthreads();
    if (q != 0) return;

    // wave 0: combine quarters, bias+relu, store h
    #pragma unroll
    for (int o = 0; o < FOUT; ++o)
        acc[o] += (sm[0][a][o] + sm[1][a][o]) + sm[2][a][o];

    if (act) {
        const float* bg = type_b + (size_t)g * FOUT;
        #pragma unroll
        for (int o = 0; o < FOUT; ++o)
            acc[o] = fmaxf(acc[o] + bg[o], 0.0f);
        float* hp = h + ((size_t)b * Nn + n) * HPAD;
        float4* hp4 = reinterpret_cast<float4*>(hp);
        #pragma unroll
        for (int i = 0; i < 6; ++i) {
            float4 v;
            v.x = acc[4 * i + 0]; v.y = acc[4 * i + 1];
            v.z = acc[4 * i + 2]; v.w = acc[4 * i + 3];
            hp4[i] = v;
        }
        hp[24] = acc[24];
    } else {
        #pragma unroll
        for (int o = 0; o < FOUT; ++o) acc[o] = 0.0f;
    }

    // BN partials: butterfly {1,2,4,8} -> per-16-lane-group sums
    float bs[FOUT], bq[FOUT];
    #pragma unroll
    for (int o = 0; o < FOUT; ++o) {
        float s = acc[o];
        float qq = acc[o] * acc[o];
        s += __shfl_xor(s, 1, 64);  qq += __shfl_xor(qq, 1, 64);
        s += __shfl_xor(s, 2, 64);  qq += __shfl_xor(qq, 2, 64);
        s += __shfl_xor(s, 4, 64);  qq += __shfl_xor(qq, 4, 64);
        s += __shfl_xor(s, 8, 64);  qq += __shfl_xor(qq, 8, 64);
        bs[o] = s; bq[o] = qq;
    }
    const int row = blk * 4 + (a >> 4);
    if ((a & 15) == 0) {
        #pragma unroll
        for (int o = 0; o < FOUT; ++o) {
            psum[(size_t)o * NPART + row] = bs[o];
            psq [(size_t)o * NPART + row] = bq[o];
        }
    }
}

// ---------------------------------------------------------------------------
// K2: reduce partials -> per-channel affine A, C.
// 25 blocks (one channel each) x 64 threads; coalesced float4 streams.
// ---------------------------------------------------------------------------
__global__ void k2_bnstats(
    const float* __restrict__ psum,      // [FOUT][NPART]
    const float* __restrict__ psq,       // [FOUT][NPART]
    const float* __restrict__ gamma,
    const float* __restrict__ beta,
    float* __restrict__ AC)              // [50]: A[0..24], C[25..49]
{
    const int c = blockIdx.x;            // channel 0..24
    const int lane = threadIdx.x;        // 64
    const float4* ps4 = reinterpret_cast<const float4*>(psum + (size_t)c * NPART);
    const float4* pq4 = reinterpret_cast<const float4*>(psq  + (size_t)c * NPART);
    float s1 = 0.0f, s2 = 0.0f;
    for (int i = lane; i < NPART / 4; i += 64) {
        float4 v = ps4[i]; s1 += (v.x + v.y) + (v.z + v.w);
        float4 q = pq4[i]; s2 += (q.x + q.y) + (q.z + q.w);
    }
    #pragma unroll
    for (int m = 1; m < 64; m <<= 1) {
        s1 += __shfl_xor(s1, m, 64);
        s2 += __shfl_xor(s2, m, 64);
    }
    if (lane == 0) {
        const float inv_cnt = 1.0f / (float)NROWS;
        const float mean = s1 * inv_cnt;
        const float var = s2 * inv_cnt - mean * mean;
        const float a = gamma[c] * rsqrtf(var + EPSBN);
        AC[c] = a;
        AC[FOUT + c] = beta[c] - mean * a;
    }
}

// ---------------------------------------------------------------------------
// K3: gather + BN-on-the-fly + conv linear + relu + out_w dot.
// 4 threads per atom (3 neighbors each). Conv outputs split across the 4
// lanes (o = 4k+mg, no redundancy); weights read from a TRANSPOSED LDS tile
// wT[o][f] (28-float rows -> ds_read_b128, bank-conflict-free: rows 28*mg
// land on bank-quads {0,28,24,20}).
// XCD locality: b = blk & 31 -> blk%8 == b%8, one XCD per batch slab.
// ---------------------------------------------------------------------------
__global__ __launch_bounds__(256) void k3_conv(
    const float* __restrict__ h,         // [B][N][HPAD]
    const float* __restrict__ bond,      // [B][N][M]
    const int*   __restrict__ adj,       // [B][N][M]
    const float* __restrict__ AC,        // [50]
    const float* __restrict__ conv_w,    // [FOUT][FOUT]
    const float* __restrict__ conv_b,    // [FOUT]
    const float* __restrict__ out_w,     // [FOUT][1]
    float* __restrict__ pe)              // [K3_BLOCKS] block partials
{
    const int blk = blockIdx.x;
    const int b = blk & 31;
    const int chunk = blk >> 5;
    const int tid = threadIdx.x;
    const int a = tid >> 2;              // atom within chunk (0..63)
    const int mg = tid & 3;              // neighbor group / o-split lane
    const int n = chunk * 64 + a;
    const size_t row = (size_t)b * Nn + n;

    // stage transposed conv weights: wT[o][f] = conv_w[f][o], pad zeroed
    __shared__ __align__(16) float wT[FOUT][HPAD];
    for (int t = tid; t < FOUT * HPAD; t += 256) {
        const int o = t / HPAD, f = t % HPAD;
        wT[o][f] = (f < FOUT) ? conv_w[f * FOUT + o] : 0.0f;
    }

    const float* bp = bond + row * Mn + mg * 3;
    const int*   ajp = adj + row * Mn + mg * 3;
    const float w0 = bp[0], w1 = bp[1], w2 = bp[2];
    const int a0 = ajp[0], a1 = ajp[1], a2 = ajp[2];
    float bsum = w0 + w1 + w2;

    const float* hb = h + (size_t)b * Nn * HPAD;
    const float4* p0 = reinterpret_cast<const float4*>(hb + (size_t)a0 * HPAD);
    const float4* p1 = reinterpret_cast<const float4*>(hb + (size_t)a1 * HPAD);
    const float4* p2 = reinterpret_cast<const float4*>(hb + (size_t)a2 * HPAD);

    // issue all 21 gather loads up front (max MLP), then FMA
    float4 q0[7], q1[7], q2[7];
    #pragma unroll
    for (int i = 0; i < 7; ++i) q0[i] = p0[i];
    #pragma unroll
    for (int i = 0; i < 7; ++i) q1[i] = p1[i];
    #pragma unroll
    for (int i = 0; i < 7; ++i) q2[i] = p2[i];

    float msg[FOUT];
    #pragma unroll
    for (int i = 0; i < 6; ++i) {
        msg[4*i+0] = fmaf(w2, q2[i].x, fmaf(w1, q1[i].x, w0 * q0[i].x));
        msg[4*i+1] = fmaf(w2, q2[i].y, fmaf(w1, q1[i].y, w0 * q0[i].y));
        msg[4*i+2] = fmaf(w2, q2[i].z, fmaf(w1, q1[i].z, w0 * q0[i].z));
        msg[4*i+3] = fmaf(w2, q2[i].w, fmaf(w1, q1[i].w, w0 * q0[i].w));
    }
    msg[24] = fmaf(w2, q2[6].x, fmaf(w1, q1[6].x, w0 * q0[6].x));

    // reduce the 4 lanes of this atom (width-4 butterfly)
    #pragma unroll
    for (int f = 0; f < FOUT; ++f) {
        msg[f] += __shfl_xor(msg[f], 1, 64);
        msg[f] += __shfl_xor(msg[f], 2, 64);
    }
    bsum += __shfl_xor(bsum, 1, 64);
    bsum += __shfl_xor(bsum, 2, 64);

    // BN affine on the fly; pad msgn to 28 with zeros for b128 weight rows
    float msgn[HPAD];
    #pragma unroll
    for (int f = 0; f < FOUT; ++f)
        msgn[f] = AC[f] * msg[f] + AC[FOUT + f] * bsum;
    msgn[25] = 0.0f; msgn[26] = 0.0f; msgn[27] = 0.0f;

    __syncthreads();   // wT staged (written at top) before any lane reads it

    // conv outputs o = 4k + mg, weights via ds_read_b128 from wT[o]
    float v = 0.0f;
    #pragma unroll
    for (int k = 0; k < 7; ++k) {
        const int o = 4 * k + mg;
        if (o < FOUT) {
            float t = conv_b[o];
            const float4* wrow = reinterpret_cast<const float4*>(&wT[o][0]);
            #pragma unroll
            for (int j = 0; j < 7; ++j) {
                const float4 w4 = wrow[j];
                t = fmaf(msgn[4*j+0], w4.x, t);
                t = fmaf(msgn[4*j+1], w4.y, t);
                t = fmaf(msgn[4*j+2], w4.z, t);
                t = fmaf(msgn[4*j+3], w4.w, t);
            }
            v += fmaxf(t, 0.0f) * out_w[o];
        }
    }

    // wave butterfly (16 atoms x 4 o-partials), then 4-wave LDS
    #pragma unroll
    for (int m = 1; m < 64; m <<= 1)
        v += __shfl_xor(v, m, 64);
    __shared__ float wsum[4];
    const int wid = tid >> 6;
    if ((tid & 63) == 0) wsum[wid] = v;
    __syncthreads();
    if (tid == 0)
        pe[blk] = wsum[0] + wsum[1] + wsum[2] + wsum[3];
}

// ---------------------------------------------------------------------------
// K4: final per-batch reduce + relu.  1 block, 32 threads.
// ---------------------------------------------------------------------------
__global__ void k4_final(
    const float* __restrict__ pe,        // [K3_BLOCKS], blk = chunk*32 + b
    const float* __restrict__ out_b,
    float* __restrict__ out)             // [B]
{
    const int b = threadIdx.x;
    if (b >= Bn) return;
    float s = 0.0f;
    #pragma unroll
    for (int c = 0; c < 32; ++c) s += pe[c * 32 + b];
    const float e = s * (1.0f / (float)Nn) + out_b[0];
    out[b] = fmaxf(e, 0.0f);
}

// ---------------------------------------------------------------------------
extern "C" void kernel_launch(void* const* d_in, const int* in_sizes, int n_in,
                              void* d_out, int out_size, void* d_ws, size_t ws_size,
                              hipStream_t stream)
{
    const float* atom   = (const float*)d_in[0];
    const float* bond   = (const float*)d_in[1];
    const int*   adjm   = (const int*)  d_in[2];
    const float* type_w = (const float*)d_in[3];
    const float* type_b = (const float*)d_in[4];
    const float* gamma  = (const float*)d_in[5];
    const float* beta   = (const float*)d_in[6];
    const float* conv_w = (const float*)d_in[7];
    const float* conv_b = (const float*)d_in[8];
    const float* out_w  = (const float*)d_in[9];
    const float* out_b  = (const float*)d_in[10];
    float* out = (float*)d_out;

    float* ws = (float*)d_ws;
    float* h    = ws;                             // B*N*HPAD = 1,835,008
    float* psum = h + (size_t)Bn * Nn * HPAD;     // FOUT*NPART = 105,600
    float* psq  = psum + (size_t)FOUT * NPART;    // 105,600
    float* AC   = psq + (size_t)FOUT * NPART;     // 50 (pad 64)
    float* pe   = AC + 64;                        // 1024

    k1_typelinear<<<K1_BLOCKS, 256, 0, stream>>>(atom, type_w, type_b, h, psum, psq);
    k2_bnstats<<<FOUT, 64, 0, stream>>>(psum, psq, gamma, beta, AC);
    k3_conv<<<K3_BLOCKS, 256, 0, stream>>>(h, bond, adjm, AC, conv_w, conv_b, out_w, pe);
    k4_final<<<1, 32, 0, stream>>>(pe, out_b, out);
}

// Round 6
// 43.180 us; speedup vs baseline: 2.2656x; 1.3357x over previous
//
#include <hip/hip_runtime.h>
#include <hip/hip_bf16.h>

// Problem constants
#define Bn 32
#define Nn 2048
#define Mn 12
#define FIN 64
#define FOUT 25
#define HPAD 28            // padded h row (floats) for float4 alignment
#define EPSBN 1e-5f

#define K1_BLOCKS 1056     // 32 b * 3 groups * 11 chunks(64 atoms)
#define NPART (K1_BLOCKS * 4)   // BN partial rows (4 x 16-lane groups of wave 0)
#define K3_BLOCKS 1024     // 32 chunks(64 atoms) * 32 b
#define NROWS 65536        // B*N

// ---------------------------------------------------------------------------
// K1: grouped linear + relu -> h[B][N][HPAD]; BN partials.
// 4-way K-split BY WAVE: wave q owns input features [16q,16q+16).
// CRITICAL: q must be pinned to SGPR via readfirstlane — tid>>6 alone is
// divergent to LLVM's uniformity analysis, which turns every weight load
// into scattered global_load_dword (round-4 regression, +17 us). With q in
// an SGPR and g block-uniform, all weight indices are uniform-base +
// compile-time offset -> s_load weights, VALU is pure v_fmac.
// ---------------------------------------------------------------------------
__global__ __launch_bounds__(256) void k1_typelinear(
    const float* __restrict__ atom,      // [B][N][FIN]
    const float* __restrict__ type_w,    // [3][FIN][FOUT]
    const float* __restrict__ type_b,    // [3][FOUT]
    float* __restrict__ h,               // [B][N][HPAD]
    float* __restrict__ psum,            // [FOUT][NPART]
    float* __restrict__ psq)             // [FOUT][NPART]
{
    const int blk = blockIdx.x;
    const int b = blk / 33;
    const int rem = blk % 33;
    const int g = rem / 11;
    const int chunk = rem % 11;
    const int starts[4] = {0, 683, 1366, 2048};
    const int s0 = starts[g];
    const int e0 = starts[g + 1];
    const int tid = threadIdx.x;
    const int a = tid & 63;              // atom within chunk
    const int q = __builtin_amdgcn_readfirstlane(tid >> 6);  // SGPR wave id
    const int n = s0 + chunk * 64 + a;
    const bool act = (n < e0);

    float acc[FOUT];
    #pragma unroll
    for (int o = 0; o < FOUT; ++o) acc[o] = 0.0f;

    if (act) {
        // 16 input features for this quarter: 4 x float4
        float av[16];
        const float4* ap = reinterpret_cast<const float4*>(
            atom + ((size_t)b * Nn + n) * FIN + q * 16);
        #pragma unroll
        for (int i = 0; i < 4; ++i) {
            float4 v = ap[i];
            av[4 * i + 0] = v.x; av[4 * i + 1] = v.y;
            av[4 * i + 2] = v.z; av[4 * i + 3] = v.w;
        }
        const float* wg = type_w + (size_t)g * (FIN * FOUT) + q * 16 * FOUT;
        #pragma unroll
        for (int f = 0; f < 16; ++f) {
            const float x = av[f];
            #pragma unroll
            for (int o = 0; o < FOUT; ++o)
                acc[o] = fmaf(x, wg[f * FOUT + o], acc[o]);  // s_load weights
        }
    }

    __shared__ float sm[3][64][26];      // stride 26: 2-way conflict (free)
    if (q > 0) {
        #pragma unroll
        for (int o = 0; o < FOUT; ++o) sm[q - 1][a][o] = acc[o];
    }
    __syncthreads();
    if (q != 0) return;

    // wave 0: combine quarters, bias+relu, store h
    #pragma unroll
    for (int o = 0; o < FOUT; ++o)
        acc[o] += (sm[0][a][o] + sm[1][a][o]) + sm[2][a][o];

    if (act) {
        const float* bg = type_b + (size_t)g * FOUT;
        #pragma unroll
        for (int o = 0; o < FOUT; ++o)
            acc[o] = fmaxf(acc[o] + bg[o], 0.0f);
        float* hp = h + ((size_t)b * Nn + n) * HPAD;
        float4* hp4 = reinterpret_cast<float4*>(hp);
        #pragma unroll
        for (int i = 0; i < 6; ++i) {
            float4 v;
            v.x = acc[4 * i + 0]; v.y = acc[4 * i + 1];
            v.z = acc[4 * i + 2]; v.w = acc[4 * i + 3];
            hp4[i] = v;
        }
        hp[24] = acc[24];
    } else {
        #pragma unroll
        for (int o = 0; o < FOUT; ++o) acc[o] = 0.0f;
    }

    // BN partials: butterfly {1,2,4,8} -> per-16-lane-group sums
    float bs[FOUT], bq[FOUT];
    #pragma unroll
    for (int o = 0; o < FOUT; ++o) {
        float s = acc[o];
        float qq = acc[o] * acc[o];
        s += __shfl_xor(s, 1, 64);  qq += __shfl_xor(qq, 1, 64);
        s += __shfl_xor(s, 2, 64);  qq += __shfl_xor(qq, 2, 64);
        s += __shfl_xor(s, 4, 64);  qq += __shfl_xor(qq, 4, 64);
        s += __shfl_xor(s, 8, 64);  qq += __shfl_xor(qq, 8, 64);
        bs[o] = s; bq[o] = qq;
    }
    const int row = blk * 4 + (a >> 4);
    if ((a & 15) == 0) {
        #pragma unroll
        for (int o = 0; o < FOUT; ++o) {
            psum[(size_t)o * NPART + row] = bs[o];
            psq [(size_t)o * NPART + row] = bq[o];
        }
    }
}

// ---------------------------------------------------------------------------
// K2: reduce partials -> per-channel affine A, C.
// 25 blocks (one channel each) x 64 threads; coalesced float4 streams.
// ---------------------------------------------------------------------------
__global__ void k2_bnstats(
    const float* __restrict__ psum,      // [FOUT][NPART]
    const float* __restrict__ psq,       // [FOUT][NPART]
    const float* __restrict__ gamma,
    const float* __restrict__ beta,
    float* __restrict__ AC)              // [50]: A[0..24], C[25..49]
{
    const int c = blockIdx.x;            // channel 0..24
    const int lane = threadIdx.x;        // 64
    const float4* ps4 = reinterpret_cast<const float4*>(psum + (size_t)c * NPART);
    const float4* pq4 = reinterpret_cast<const float4*>(psq  + (size_t)c * NPART);
    float s1 = 0.0f, s2 = 0.0f;
    for (int i = lane; i < NPART / 4; i += 64) {
        float4 v = ps4[i]; s1 += (v.x + v.y) + (v.z + v.w);
        float4 q = pq4[i]; s2 += (q.x + q.y) + (q.z + q.w);
    }
    #pragma unroll
    for (int m = 1; m < 64; m <<= 1) {
        s1 += __shfl_xor(s1, m, 64);
        s2 += __shfl_xor(s2, m, 64);
    }
    if (lane == 0) {
        const float inv_cnt = 1.0f / (float)NROWS;
        const float mean = s1 * inv_cnt;
        const float var = s2 * inv_cnt - mean * mean;
        const float a = gamma[c] * rsqrtf(var + EPSBN);
        AC[c] = a;
        AC[FOUT + c] = beta[c] - mean * a;
    }
}

// ---------------------------------------------------------------------------
// K3: gather + BN-on-the-fly + conv linear + relu + out_w dot.
// 4 threads per atom (3 neighbors each). Conv outputs split across the 4
// lanes (o = 4k+mg); weights from a TRANSPOSED LDS tile wT[o][0..27] with
// conv_b folded into col 25 (msgn[25]=1) and out_w into col 26 (extracted
// from the j=6 b128 read) -> zero per-lane scalar global loads in epilogue.
// XCD locality: b = blk & 31 -> blk%8 == b%8, one XCD per batch slab.
// ---------------------------------------------------------------------------
__global__ __launch_bounds__(256) void k3_conv(
    const float* __restrict__ h,         // [B][N][HPAD]
    const float* __restrict__ bond,      // [B][N][M]
    const int*   __restrict__ adj,       // [B][N][M]
    const float* __restrict__ AC,        // [50]
    const float* __restrict__ conv_w,    // [FOUT][FOUT]
    const float* __restrict__ conv_b,    // [FOUT]
    const float* __restrict__ out_w,     // [FOUT][1]
    float* __restrict__ pe)              // [K3_BLOCKS] block partials
{
    const int blk = blockIdx.x;
    const int b = blk & 31;
    const int chunk = blk >> 5;
    const int tid = threadIdx.x;
    const int a = tid >> 2;              // atom within chunk (0..63)
    const int mg = tid & 3;              // neighbor group / o-split lane
    const int n = chunk * 64 + a;
    const size_t row = (size_t)b * Nn + n;

    // stage wT[o][f]: f<25 -> conv_w[f][o]; 25 -> conv_b[o]; 26 -> out_w[o]
    __shared__ __align__(16) float wT[FOUT][HPAD];
    for (int t = tid; t < FOUT * HPAD; t += 256) {
        const int o = t / HPAD, f = t - o * HPAD;
        float wv = 0.0f;
        if (f < FOUT)      wv = conv_w[f * FOUT + o];
        else if (f == 25)  wv = conv_b[o];
        else if (f == 26)  wv = out_w[o];
        wT[o][f] = wv;
    }

    const float* bp = bond + row * Mn + mg * 3;
    const int*   ajp = adj + row * Mn + mg * 3;
    const float w0 = bp[0], w1 = bp[1], w2 = bp[2];
    const int a0 = ajp[0], a1 = ajp[1], a2 = ajp[2];
    float bsum = w0 + w1 + w2;

    const float* hb = h + (size_t)b * Nn * HPAD;
    const float4* p0 = reinterpret_cast<const float4*>(hb + (size_t)a0 * HPAD);
    const float4* p1 = reinterpret_cast<const float4*>(hb + (size_t)a1 * HPAD);
    const float4* p2 = reinterpret_cast<const float4*>(hb + (size_t)a2 * HPAD);

    // issue all 21 gather loads up front (max MLP), then FMA
    float4 q0[7], q1[7], q2[7];
    #pragma unroll
    for (int i = 0; i < 7; ++i) q0[i] = p0[i];
    #pragma unroll
    for (int i = 0; i < 7; ++i) q1[i] = p1[i];
    #pragma unroll
    for (int i = 0; i < 7; ++i) q2[i] = p2[i];

    float msg[FOUT];
    #pragma unroll
    for (int i = 0; i < 6; ++i) {
        msg[4*i+0] = fmaf(w2, q2[i].x, fmaf(w1, q1[i].x, w0 * q0[i].x));
        msg[4*i+1] = fmaf(w2, q2[i].y, fmaf(w1, q1[i].y, w0 * q0[i].y));
        msg[4*i+2] = fmaf(w2, q2[i].z, fmaf(w1, q1[i].z, w0 * q0[i].z));
        msg[4*i+3] = fmaf(w2, q2[i].w, fmaf(w1, q1[i].w, w0 * q0[i].w));
    }
    msg[24] = fmaf(w2, q2[6].x, fmaf(w1, q1[6].x, w0 * q0[6].x));

    // reduce the 4 lanes of this atom (width-4 butterfly)
    #pragma unroll
    for (int f = 0; f < FOUT; ++f) {
        msg[f] += __shfl_xor(msg[f], 1, 64);
        msg[f] += __shfl_xor(msg[f], 2, 64);
    }
    bsum += __shfl_xor(bsum, 1, 64);
    bsum += __shfl_xor(bsum, 2, 64);

    // BN affine on the fly; pad: [25]=1 picks up conv_b, [26]/[27] dead
    float msgn[HPAD];
    #pragma unroll
    for (int f = 0; f < FOUT; ++f)
        msgn[f] = AC[f] * msg[f] + AC[FOUT + f] * bsum;
    msgn[25] = 1.0f; msgn[26] = 0.0f; msgn[27] = 0.0f;

    __syncthreads();   // wT staged (written at top) before any lane reads it

    // conv outputs o = 4k + mg, weights via ds_read_b128 from wT[o]
    float v = 0.0f;
    #pragma unroll
    for (int k = 0; k < 7; ++k) {
        const int o = 4 * k + mg;
        if (o < FOUT) {
            float t = 0.0f;
            float myow = 0.0f;
            const float4* wrow = reinterpret_cast<const float4*>(&wT[o][0]);
            #pragma unroll
            for (int j = 0; j < 7; ++j) {
                const float4 w4 = wrow[j];
                t = fmaf(msgn[4*j+0], w4.x, t);
                t = fmaf(msgn[4*j+1], w4.y, t);
                t = fmaf(msgn[4*j+2], w4.z, t);
                t = fmaf(msgn[4*j+3], w4.w, t);
                if (j == 6) myow = w4.z;   // wT[o][26] = out_w[o]
            }
            v += fmaxf(t, 0.0f) * myow;
        }
    }

    // wave butterfly (16 atoms x 4 o-partials), then 4-wave LDS
    #pragma unroll
    for (int m = 1; m < 64; m <<= 1)
        v += __shfl_xor(v, m, 64);
    __shared__ float wsum[4];
    const int wid = tid >> 6;
    if ((tid & 63) == 0) wsum[wid] = v;
    __syncthreads();
    if (tid == 0)
        pe[blk] = wsum[0] + wsum[1] + wsum[2] + wsum[3];
}

// ---------------------------------------------------------------------------
// K4: final per-batch reduce + relu.  1 block, 32 threads.
// ---------------------------------------------------------------------------
__global__ void k4_final(
    const float* __restrict__ pe,        // [K3_BLOCKS], blk = chunk*32 + b
    const float* __restrict__ out_b,
    float* __restrict__ out)             // [B]
{
    const int b = threadIdx.x;
    if (b >= Bn) return;
    float s = 0.0f;
    #pragma unroll
    for (int c = 0; c < 32; ++c) s += pe[c * 32 + b];
    const float e = s * (1.0f / (float)Nn) + out_b[0];
    out[b] = fmaxf(e, 0.0f);
}

// ---------------------------------------------------------------------------
extern "C" void kernel_launch(void* const* d_in, const int* in_sizes, int n_in,
                              void* d_out, int out_size, void* d_ws, size_t ws_size,
                              hipStream_t stream)
{
    const float* atom   = (const float*)d_in[0];
    const float* bond   = (const float*)d_in[1];
    const int*   adjm   = (const int*)  d_in[2];
    const float* type_w = (const float*)d_in[3];
    const float* type_b = (const float*)d_in[4];
    const float* gamma  = (const float*)d_in[5];
    const float* beta   = (const float*)d_in[6];
    const float* conv_w = (const float*)d_in[7];
    const float* conv_b = (const float*)d_in[8];
    const float* out_w  = (const float*)d_in[9];
    const float* out_b  = (const float*)d_in[10];
    float* out = (float*)d_out;

    float* ws = (float*)d_ws;
    float* h    = ws;                             // B*N*HPAD = 1,835,008
    float* psum = h + (size_t)Bn * Nn * HPAD;     // FOUT*NPART = 105,600
    float* psq  = psum + (size_t)FOUT * NPART;    // 105,600
    float* AC   = psq + (size_t)FOUT * NPART;     // 50 (pad 64)
    float* pe   = AC + 64;                        // 1024

    k1_typelinear<<<K1_BLOCKS, 256, 0, stream>>>(atom, type_w, type_b, h, psum, psq);
    k2_bnstats<<<FOUT, 64, 0, stream>>>(psum, psq, gamma, beta, AC);
    k3_conv<<<K3_BLOCKS, 256, 0, stream>>>(h, bond, adjm, AC, conv_w, conv_b, out_w, pe);
    k4_final<<<1, 32, 0, stream>>>(pe, out_b, out);
}

// Round 7
// 33.338 us; speedup vs baseline: 2.9345x; 1.2952x over previous
//
#include <hip/hip_runtime.h>
#include <hip/hip_bf16.h>

// Problem constants
#define Bn 32
#define Nn 2048
#define Mn 12
#define FIN 64
#define FOUT 25
#define HROW 32            // h row stride in floats: 128 B = exactly 1 cache line
#define EPSBN 1e-5f

#define K1_BLOCKS 1056     // 32 b * 3 groups * 11 chunks(64 atoms)
#define NPART K1_BLOCKS    // one BN partial row per block (full-wave reduce)
#define K3_BLOCKS 1024     // 32 chunks(64 atoms) * 32 b
#define NROWS 65536        // B*N

// ---------------------------------------------------------------------------
// K1: grouped linear + relu -> h[B][N][HROW]; BN partials (1 row/block).
// 4-way K-split BY WAVE; q pinned to SGPR via readfirstlane (tid>>6 alone is
// divergent to LLVM uniformity analysis -> scattered loads, round-4 bug).
// ---------------------------------------------------------------------------
__global__ __launch_bounds__(256) void k1_typelinear(
    const float* __restrict__ atom,      // [B][N][FIN]
    const float* __restrict__ type_w,    // [3][FIN][FOUT]
    const float* __restrict__ type_b,    // [3][FOUT]
    float* __restrict__ h,               // [B][N][HROW]
    float* __restrict__ psum,            // [FOUT][NPART]
    float* __restrict__ psq)             // [FOUT][NPART]
{
    const int blk = blockIdx.x;
    const int b = blk / 33;
    const int rem = blk % 33;
    const int g = rem / 11;
    const int chunk = rem % 11;
    const int s0 = g * 683;
    const int e0 = (g == 2) ? 2048 : (g + 1) * 683;
    const int tid = threadIdx.x;
    const int a = tid & 63;              // atom within chunk
    const int q = __builtin_amdgcn_readfirstlane(tid >> 6);  // SGPR wave id
    const int n = s0 + chunk * 64 + a;
    const bool act = (n < e0);

    float acc[FOUT];
    #pragma unroll
    for (int o = 0; o < FOUT; ++o) acc[o] = 0.0f;

    if (act) {
        float av[16];
        const float4* ap = reinterpret_cast<const float4*>(
            atom + ((size_t)b * Nn + n) * FIN + q * 16);
        #pragma unroll
        for (int i = 0; i < 4; ++i) {
            float4 v = ap[i];
            av[4 * i + 0] = v.x; av[4 * i + 1] = v.y;
            av[4 * i + 2] = v.z; av[4 * i + 3] = v.w;
        }
        const float* wg = type_w + (size_t)g * (FIN * FOUT) + q * 16 * FOUT;
        #pragma unroll
        for (int f = 0; f < 16; ++f) {
            const float x = av[f];
            #pragma unroll
            for (int o = 0; o < FOUT; ++o)
                acc[o] = fmaf(x, wg[f * FOUT + o], acc[o]);  // s_load weights
        }
    }

    __shared__ float sm[3][64][26];      // stride 26: 2-way conflict (free)
    if (q > 0) {
        #pragma unroll
        for (int o = 0; o < FOUT; ++o) sm[q - 1][a][o] = acc[o];
    }
    __syncthreads();
    if (q != 0) return;

    // wave 0: combine quarters, bias+relu, store h
    #pragma unroll
    for (int o = 0; o < FOUT; ++o)
        acc[o] += (sm[0][a][o] + sm[1][a][o]) + sm[2][a][o];

    if (act) {
        const float* bg = type_b + (size_t)g * FOUT;
        #pragma unroll
        for (int o = 0; o < FOUT; ++o)
            acc[o] = fmaxf(acc[o] + bg[o], 0.0f);
        float* hp = h + ((size_t)b * Nn + n) * HROW;
        float4* hp4 = reinterpret_cast<float4*>(hp);
        #pragma unroll
        for (int i = 0; i < 6; ++i) {
            float4 v;
            v.x = acc[4 * i + 0]; v.y = acc[4 * i + 1];
            v.z = acc[4 * i + 2]; v.w = acc[4 * i + 3];
            hp4[i] = v;
        }
        {
            float4 v; v.x = acc[24]; v.y = 0.0f; v.z = 0.0f; v.w = 0.0f;
            hp4[6] = v;              // floats 28..31 stay unwritten (discarded)
        }
    } else {
        #pragma unroll
        for (int o = 0; o < FOUT; ++o) acc[o] = 0.0f;
    }

    // BN partials: FULL 64-lane butterfly -> every lane has block totals
    float bs[FOUT], bq[FOUT];
    #pragma unroll
    for (int o = 0; o < FOUT; ++o) {
        float s = acc[o];
        float qq = acc[o] * acc[o];
        #pragma unroll
        for (int m = 1; m < 64; m <<= 1) {
            s  += __shfl_xor(s,  m, 64);
            qq += __shfl_xor(qq, m, 64);
        }
        bs[o] = s; bq[o] = qq;
    }
    if (a == 0) {
        #pragma unroll
        for (int o = 0; o < FOUT; ++o)
            psum[(size_t)o * NPART + blk] = bs[o];
    } else if (a == 1) {
        #pragma unroll
        for (int o = 0; o < FOUT; ++o)
            psq[(size_t)o * NPART + blk] = bq[o];
    }
}

// ---------------------------------------------------------------------------
// K2: reduce partials -> affine. 25 blocks x 256 threads, coalesced float4,
// all loads independent (latency hidden by MLP). AC layout: A@[0..24] pad to
// 28, C@[28..52] (chunk-friendly for k3's per-lane float4 reads).
// ---------------------------------------------------------------------------
__global__ __launch_bounds__(256) void k2_bnstats(
    const float* __restrict__ psum,      // [FOUT][NPART]
    const float* __restrict__ psq,       // [FOUT][NPART]
    const float* __restrict__ gamma,
    const float* __restrict__ beta,
    float* __restrict__ AC)              // [64]
{
    const int c = blockIdx.x;            // channel 0..24
    const int tid = threadIdx.x;         // 256
    const int lane = tid & 63;
    const int w = tid >> 6;
    const float4* ps4 = reinterpret_cast<const float4*>(psum + (size_t)c * NPART);
    const float4* pq4 = reinterpret_cast<const float4*>(psq  + (size_t)c * NPART);
    float4 v = ps4[tid];
    float4 qv = pq4[tid];
    float s1 = (v.x + v.y) + (v.z + v.w);
    float s2 = (qv.x + qv.y) + (qv.z + qv.w);
    if (tid < (NPART / 4 - 256)) {       // 264 total float4s
        float4 v2 = ps4[tid + 256];
        float4 q2 = pq4[tid + 256];
        s1 += (v2.x + v2.y) + (v2.z + v2.w);
        s2 += (q2.x + q2.y) + (q2.z + q2.w);
    }
    #pragma unroll
    for (int m = 1; m < 64; m <<= 1) {
        s1 += __shfl_xor(s1, m, 64);
        s2 += __shfl_xor(s2, m, 64);
    }
    __shared__ float r1[4], r2[4];
    if (lane == 0) { r1[w] = s1; r2[w] = s2; }
    __syncthreads();
    if (tid == 0) {
        const float S1 = (r1[0] + r1[1]) + (r1[2] + r1[3]);
        const float S2 = (r2[0] + r2[1]) + (r2[2] + r2[3]);
        const float inv_cnt = 1.0f / (float)NROWS;
        const float mean = S1 * inv_cnt;
        const float var = S2 * inv_cnt - mean * mean;
        const float aa = gamma[c] * rsqrtf(var + EPSBN);
        AC[c] = aa;
        AC[28 + c] = beta[c] - mean * aa;
    }
}

// ---------------------------------------------------------------------------
// K3: gather + BN + conv + relu + out_w dot.
// COALESCED gather: h rows are 128B lines; 8 lanes (chunks c=0..7) per row ->
// one transaction per row (vs 64-divergent lines/instr before). Wave = 8 row
// groups; per wave 16 atoms in 2 phases of 8. Lane (g,c) accumulates msg
// chunk [4c..4c+3] over the atom's 12 neighbors, applies BN affine in-reg,
// writes msgn to a wave-private LDS tile [16][36] (conflict-free both ways).
// Epilogue: o-split conv (o=4k+mg) from transposed wT tile (conv_b folded at
// col 25 via msgn[25]=1, out_w at col 26).
// XCD locality: b = blk & 31 -> one XCD per batch slab (256 KB, L2-resident).
// ---------------------------------------------------------------------------
__global__ __launch_bounds__(256) void k3_conv(
    const float* __restrict__ h,         // [B][N][HROW]
    const float* __restrict__ bond,      // [B][N][M]
    const int*   __restrict__ adj,       // [B][N][M]
    const float* __restrict__ AC,        // [64]
    const float* __restrict__ conv_w,    // [FOUT][FOUT]
    const float* __restrict__ conv_b,    // [FOUT]
    const float* __restrict__ out_w,     // [FOUT][1]
    float* __restrict__ pe)              // [K3_BLOCKS]
{
    const int blk = blockIdx.x;
    const int b = blk & 31;
    const int chunk = blk >> 5;
    const int tid = threadIdx.x;
    const int w = tid >> 6;              // wave (LDS base only)
    const int lane = tid & 63;
    const int g = lane >> 3;             // row group 0..7
    const int c = lane & 7;              // 16B chunk in 128B row

    __shared__ __align__(16) float wT[FOUT][28];
    __shared__ __align__(16) float msgn_s[4][16][36];

    // stage wT[o][f]: f<25 -> conv_w[f][o]; 25 -> conv_b[o]; 26 -> out_w[o]
    for (int t = tid; t < FOUT * 28; t += 256) {
        const int o = t / 28, f = t - o * 28;
        float wv = 0.0f;
        if (f < FOUT)      wv = conv_w[f * FOUT + o];
        else if (f == 25)  wv = conv_b[o];
        else if (f == 26)  wv = out_w[o];
        wT[o][f] = wv;
    }

    const float* hb = h + (size_t)b * (Nn * HROW);
    const int atom0 = chunk * 64 + w * 16;

    // per-lane BN affine chunk (c=7 reads junk, discarded)
    const float4 Ai = *reinterpret_cast<const float4*>(AC + 4 * c);
    const float4 Ci = *reinterpret_cast<const float4*>(AC + 28 + 4 * c);

    __syncthreads();                     // wT visible to all waves

    #pragma unroll
    for (int p = 0; p < 2; ++p) {
        const int an = atom0 + p * 8 + g;
        const size_t arow = (size_t)b * Nn + an;
        const int4*   ajp = reinterpret_cast<const int4*>(adj + arow * Mn);
        const float4* bpp = reinterpret_cast<const float4*>(bond + arow * Mn);
        const int4 A0 = ajp[0], A1 = ajp[1], A2 = ajp[2];
        const float4 B0 = bpp[0], B1 = bpp[1], B2 = bpp[2];
        const int ai[12] = {A0.x, A0.y, A0.z, A0.w,
                            A1.x, A1.y, A1.z, A1.w,
                            A2.x, A2.y, A2.z, A2.w};
        const float bw[12] = {B0.x, B0.y, B0.z, B0.w,
                              B1.x, B1.y, B1.z, B1.w,
                              B2.x, B2.y, B2.z, B2.w};
        float4 macc = {0.0f, 0.0f, 0.0f, 0.0f};
        float bsum = 0.0f;
        #pragma unroll
        for (int j = 0; j < 12; ++j) {
            const float wj = bw[j];
            bsum += wj;
            const float4 hv = *reinterpret_cast<const float4*>(
                hb + (size_t)ai[j] * HROW + c * 4);
            macc.x = fmaf(wj, hv.x, macc.x);
            macc.y = fmaf(wj, hv.y, macc.y);
            macc.z = fmaf(wj, hv.z, macc.z);
            macc.w = fmaf(wj, hv.w, macc.w);
        }
        if (c < 7) {
            float4 mn;
            mn.x = fmaf(Ai.x, macc.x, Ci.x * bsum);
            mn.y = fmaf(Ai.y, macc.y, Ci.y * bsum);
            mn.z = fmaf(Ai.z, macc.z, Ci.z * bsum);
            mn.w = fmaf(Ai.w, macc.w, Ci.w * bsum);
            if (c == 6) { mn.y = 1.0f; mn.z = 0.0f; mn.w = 0.0f; }
            *reinterpret_cast<float4*>(&msgn_s[w][p * 8 + g][4 * c]) = mn;
        }
    }

    __syncthreads();                     // msgn tiles complete (belt&braces)

    // conv epilogue: lane = (a16, mg), o = 4k + mg
    const int a16 = lane >> 2;
    const int mg = lane & 3;
    const float* mrow = &msgn_s[w][a16][0];
    float msv[28];
    #pragma unroll
    for (int j = 0; j < 7; ++j) {
        const float4 mv = *reinterpret_cast<const float4*>(mrow + 4 * j);
        msv[4 * j + 0] = mv.x; msv[4 * j + 1] = mv.y;
        msv[4 * j + 2] = mv.z; msv[4 * j + 3] = mv.w;
    }
    float v = 0.0f;
    #pragma unroll
    for (int k = 0; k < 7; ++k) {
        const int o = 4 * k + mg;
        if (o < FOUT) {
            const float4* wrow = reinterpret_cast<const float4*>(&wT[o][0]);
            float t = 0.0f, myow = 0.0f;
            #pragma unroll
            for (int j = 0; j < 7; ++j) {
                const float4 w4 = wrow[j];
                t = fmaf(msv[4 * j + 0], w4.x, t);
                t = fmaf(msv[4 * j + 1], w4.y, t);
                t = fmaf(msv[4 * j + 2], w4.z, t);
                t = fmaf(msv[4 * j + 3], w4.w, t);
                if (j == 6) myow = w4.z;   // wT[o][26] = out_w[o]
            }
            v += fmaxf(t, 0.0f) * myow;
        }
    }

    #pragma unroll
    for (int m = 1; m < 64; m <<= 1)
        v += __shfl_xor(v, m, 64);
    __shared__ float wsum[4];
    if (lane == 0) wsum[w] = v;
    __syncthreads();
    if (tid == 0)
        pe[blk] = (wsum[0] + wsum[1]) + (wsum[2] + wsum[3]);
}

// ---------------------------------------------------------------------------
// K4: final per-batch reduce + relu. 1 block x 256 threads, coalesced.
// pe[blk]: blk = chunk*32 + b  ->  idx & 31 = b.
// ---------------------------------------------------------------------------
__global__ __launch_bounds__(256) void k4_final(
    const float* __restrict__ pe,        // [K3_BLOCKS]
    const float* __restrict__ out_b,
    float* __restrict__ out)             // [B]
{
    const int tid = threadIdx.x;
    const float s = (pe[tid] + pe[tid + 256]) + (pe[tid + 512] + pe[tid + 768]);
    __shared__ float sred[8][33];
    sred[tid >> 5][tid & 31] = s;
    __syncthreads();
    if (tid < Bn) {
        float t = 0.0f;
        #pragma unroll
        for (int cg = 0; cg < 8; ++cg) t += sred[cg][tid];
        out[tid] = fmaxf(t * (1.0f / (float)Nn) + out_b[0], 0.0f);
    }
}

// ---------------------------------------------------------------------------
extern "C" void kernel_launch(void* const* d_in, const int* in_sizes, int n_in,
                              void* d_out, int out_size, void* d_ws, size_t ws_size,
                              hipStream_t stream)
{
    const float* atom   = (const float*)d_in[0];
    const float* bond   = (const float*)d_in[1];
    const int*   adjm   = (const int*)  d_in[2];
    const float* type_w = (const float*)d_in[3];
    const float* type_b = (const float*)d_in[4];
    const float* gamma  = (const float*)d_in[5];
    const float* beta   = (const float*)d_in[6];
    const float* conv_w = (const float*)d_in[7];
    const float* conv_b = (const float*)d_in[8];
    const float* out_w  = (const float*)d_in[9];
    const float* out_b  = (const float*)d_in[10];
    float* out = (float*)d_out;

    float* ws = (float*)d_ws;
    float* h    = ws;                             // B*N*HROW = 2,097,152
    float* psum = h + (size_t)Bn * Nn * HROW;     // FOUT*NPART = 26,400
    float* psq  = psum + (size_t)FOUT * NPART;    // 26,400
    float* AC   = psq + (size_t)FOUT * NPART;     // 64
    float* pe   = AC + 64;                        // 1024

    k1_typelinear<<<K1_BLOCKS, 256, 0, stream>>>(atom, type_w, type_b, h, psum, psq);
    k2_bnstats<<<FOUT, 256, 0, stream>>>(psum, psq, gamma, beta, AC);
    k3_conv<<<K3_BLOCKS, 256, 0, stream>>>(h, bond, adjm, AC, conv_w, conv_b, out_w, pe);
    k4_final<<<1, 256, 0, stream>>>(pe, out_b, out);
}